// Round 5
// baseline (319.442 us; speedup 1.0000x reference)
//
#include <hip/hip_runtime.h>
#include <stdint.h>

// MHA fused: qkv-proj (ring-3 counted-vmcnt GEMM) -> causal flash attn -> out-proj (ring-4)
// B=2, S=2048, H=2048, heads=16, D=128.

using bf16x8 = __attribute__((ext_vector_type(8))) __bf16;
using f32x4  = __attribute__((ext_vector_type(4))) float;

#define S_LEN 2048
#define HID   2048
#define NHEAD 16
#define DHEAD 128
#define KDIM  2048
// 1/sqrt(128) * log2(e): attention softmax runs in exp2 domain
#define QSCALE_L2E (0.08838834764831845f * 1.4426950408889634f)

__device__ __forceinline__ unsigned short f2bf(float f) {
  union { float f; unsigned int u; } c; c.f = f;
  unsigned int u = c.u;
  return (unsigned short)((u + 0x7FFFu + ((u >> 16) & 1u)) >> 16);  // RNE
}

__device__ __forceinline__ unsigned int pkbf(float a, float b) {
  union { __bf16 h[2]; unsigned int u; } x;
  x.h[0] = (__bf16)a; x.h[1] = (__bf16)b;
  return x.u;
}

__device__ __forceinline__ void gload_lds16(const void* g, void* l) {
  __builtin_amdgcn_global_load_lds(
      (const __attribute__((address_space(1))) unsigned int*)g,
      (__attribute__((address_space(3))) unsigned int*)l, 16, 0, 0);
}

__device__ __forceinline__ f32x4 mfma16(bf16x8 a, bf16x8 b, f32x4 c) {
  return __builtin_amdgcn_mfma_f32_16x16x32_bf16(a, b, c, 0, 0, 0);
}

__device__ __forceinline__ float hmax4(f32x4 v) {
  return fmaxf(fmaxf(v[0], v[1]), fmaxf(v[2], v[3]));
}

__global__ void cvt_bf16(const float* __restrict__ in, unsigned short* __restrict__ out, int n) {
  const int n4 = n >> 2;
  const int stride = gridDim.x * blockDim.x;
  for (int i = blockIdx.x * blockDim.x + threadIdx.x; i < n4; i += stride) {
    float4 v = reinterpret_cast<const float4*>(in)[i];
    ushort4 o;
    o.x = f2bf(v.x); o.y = f2bf(v.y); o.z = f2bf(v.z); o.w = f2bf(v.w);
    reinterpret_cast<ushort4*>(out)[i] = o;
  }
}

// Shared asm helpers
#define BAR   asm volatile("s_barrier" ::: "memory")
#define VM(n) asm volatile("s_waitcnt vmcnt(" #n ")" ::: "memory")
#define PRIO1 __builtin_amdgcn_s_setprio(1)
#define PRIO0 __builtin_amdgcn_s_setprio(0)

// LDS row swizzle for 64B rows (BK=32 bf16): byte col c -> c ^ (((r>>1)&3)<<4).
// Bank check: lane set {r in 16 consecutive rows} x {kg*16}: word = 16(r&1)+4(kg^slot(r))
// -> exactly 8 accesses per bank per wave64 b128 (uniform) = conflict-free.

// ============================================================================
// QKV GEMM: C(4096 x 6144) = A * Wqkv^T + b, scatter epilogue to Q/K/Vt.
// Tile 256x384, grid 16x16 = 256 blocks (exactly one residency round).
// 512 thr = 8 waves (2m x 4n), wave tile 128x96 (acc 8x6).
// BK=32, ring-3 LDS (A 3x16KB, B 3x24KB = 120KB). Stage chunk t+2 during t.
// Per K-tile 2 phases; ONE vmcnt(5) per K-tile (at ph2 end), never 0 till drain.
// Ledger: end of tile t outstanding = chunk t+1 (5 loads) + t+2 (5) = 10;
// vmcnt(5) -> t+1 fully landed before any wave enters tile t+1.  Lead time for
// a chunk = 2 K-tiles (~4000 cy) >> HBM latency (~900 cy).
// ============================================================================
__global__ __launch_bounds__(512) void gemm_qkv(
    const unsigned short* __restrict__ A, const unsigned short* __restrict__ Bw,
    const float* __restrict__ bias,
    unsigned short* __restrict__ q_out, unsigned short* __restrict__ k_out,
    unsigned short* __restrict__ vt_out)
{
  constexpr int ABYT = 256 * 64;   // 16 KB per A chunk
  constexpr int BBYT = 384 * 64;   // 24 KB per B chunk
  __shared__ char lsA[3 * ABYT];
  __shared__ char lsB[3 * BBYT];

  const int tid = threadIdx.x, l = tid & 63, w = tid >> 6;
  const int wr = w >> 2, wc = w & 3;
  const int row16 = l & 15, kg = l >> 4;

  // XCD-chunked swizzle (256 % 8 == 0, bijective): 32 consecutive swz per XCD
  const int bid = blockIdx.x;
  const int swz = (bid & 7) * 32 + (bid >> 3);
  const int bm = (swz & 15) * 256, bn = (swz >> 4) * 384;
  const char* Ag = (const char*)A + (size_t)bm * (KDIM * 2);
  const char* Bg = (const char*)Bw + (size_t)bn * (KDIM * 2);

  f32x4 acc[8][6] = {};

  // stage chunk cc (k-cols cc*32..+31) into given slot base; linear LDS dest,
  // inverse-swizzled per-lane global source
#define STAGE_A(cc, dstb) do { _Pragma("unroll")                               \
    for (int p = 0; p < 2; ++p) {                                              \
      const int o = p * 8192 + tid * 16;                                       \
      const int r = o >> 6, c = o & 63;                                        \
      gload_lds16(Ag + (size_t)r * (KDIM * 2) + (cc) * 64 +                    \
                  (c ^ (((r >> 1) & 3) << 4)),                                 \
                  (dstb) + p * 8192 + (w << 10));                              \
    } } while (0)

#define STAGE_B(cc, dstb) do { _Pragma("unroll")                               \
    for (int p = 0; p < 3; ++p) {                                              \
      const int o = p * 8192 + tid * 16;                                       \
      const int r = o >> 6, c = o & 63;                                        \
      gload_lds16(Bg + (size_t)r * (KDIM * 2) + (cc) * 64 +                    \
                  (c ^ (((r >> 1) & 3) << 4)),                                 \
                  (dstb) + p * 8192 + (w << 10));                              \
    } } while (0)

  // prologue: chunks 0,1 into slots 0,1
  STAGE_A(0, lsA); STAGE_B(0, lsB);
  STAGE_A(1, lsA + ABYT); STAGE_B(1, lsB + BBYT);
  VM(5);            // chunk 0 landed; chunk 1 in flight
  BAR;

  int sl = 0;
  #pragma unroll 1
  for (int t = 0; t < 64; ++t) {
    const int s2 = (sl == 0) ? 2 : sl - 1;        // (sl+2) mod 3
    const char* Ac = lsA + sl * ABYT;
    const char* Bc = lsB + sl * BBYT;
    char* A2 = lsA + s2 * ABYT;
    char* B2 = lsB + s2 * BBYT;

    bf16x8 af[8], bl[3], bh[3];
    // ---- phase 1: stage A(t+2); read all A frags + B-lo; MFMA n-subtiles 0-2
    if (t < 62) STAGE_A(t + 2, A2);
    #pragma unroll
    for (int i = 0; i < 8; ++i) {
      const int m = wr * 128 + i * 16 + row16;
      af[i] = *(const bf16x8*)(Ac + m * 64 + ((kg * 16) ^ (((m >> 1) & 3) << 4)));
    }
    #pragma unroll
    for (int j = 0; j < 3; ++j) {
      const int n = wc * 96 + j * 16 + row16;
      bl[j] = *(const bf16x8*)(Bc + n * 64 + ((kg * 16) ^ (((n >> 1) & 3) << 4)));
    }
    PRIO1;
    #pragma unroll
    for (int i = 0; i < 8; ++i)
      #pragma unroll
      for (int j = 0; j < 3; ++j)
        acc[i][j] = mfma16(af[i], bl[j], acc[i][j]);
    PRIO0;
    BAR;

    // ---- phase 2: stage B(t+2); read B-hi; MFMA n-subtiles 3-5
    if (t < 62) STAGE_B(t + 2, B2);
    #pragma unroll
    for (int j = 0; j < 3; ++j) {
      const int n = wc * 96 + (j + 3) * 16 + row16;
      bh[j] = *(const bf16x8*)(Bc + n * 64 + ((kg * 16) ^ (((n >> 1) & 3) << 4)));
    }
    PRIO1;
    #pragma unroll
    for (int i = 0; i < 8; ++i)
      #pragma unroll
      for (int j = 0; j < 3; ++j)
        acc[i][j + 3] = mfma16(af[i], bh[j], acc[i][j + 3]);
    PRIO0;
    if (t < 62)      VM(5);   // chunk t+1 landed; t+2 stays in flight
    else if (t == 62) VM(0);  // drain: chunk 63 landed
    BAR;

    sl = (sl == 2) ? 0 : sl + 1;
  }
#undef STAGE_A
#undef STAGE_B

  // scatter epilogue: C/D layout col = lane&15, row = (lane>>4)*4 + reg
  #pragma unroll
  for (int j = 0; j < 6; ++j) {
    const int col = bn + wc * 96 + j * 16 + row16;
    const float bvj = bias[col];
    const int sec = col >> 11;           // 0=Q 1=K 2=V
    const int within = col & 2047;
    const int head = within >> 7, d = within & 127;
    #pragma unroll
    for (int i = 0; i < 8; ++i) {
      const int row = bm + wr * 128 + i * 16 + kg * 4;
      #pragma unroll
      for (int r = 0; r < 4; ++r) {
        const int rr = row + r;
        const int b = rr >> 11, s = rr & 2047;
        const int bh2 = b * NHEAD + head;
        const float v = acc[i][j][r] + bvj;
        if (sec == 0)
          q_out[((size_t)bh2 * S_LEN + s) * DHEAD + d] = f2bf(v * QSCALE_L2E);
        else if (sec == 1)
          k_out[((size_t)bh2 * S_LEN + s) * DHEAD + d] = f2bf(v);
        else  // V stored transposed per head: Vt[bh][d][s]
          vt_out[((size_t)bh2 * DHEAD + d) * S_LEN + s] = f2bf(v);
      }
    }
  }
}

// ============================================================================
// Out-projection: C(4096 x 2048) = A * Wout^T + b, fp32 output.
// Tile 128x256, grid 32x8 = 256 blocks exact. 8 waves (2m x 4n), wave 64x64.
// BK=32, ring-4 (A 4x8KB, B 4x16KB = 96KB). Stage t+3 during t; vmcnt(6)/tile.
// ============================================================================
__global__ __launch_bounds__(512) void gemm_out(
    const unsigned short* __restrict__ A, const unsigned short* __restrict__ Bw,
    const float* __restrict__ bias, float* __restrict__ c_out)
{
  constexpr int ABYT = 128 * 64;   // 8 KB
  constexpr int BBYT = 256 * 64;   // 16 KB
  __shared__ char lsA[4 * ABYT];
  __shared__ char lsB[4 * BBYT];

  const int tid = threadIdx.x, l = tid & 63, w = tid >> 6;
  const int wr = w >> 2, wc = w & 3;
  const int row16 = l & 15, kg = l >> 4;

  const int bid = blockIdx.x;
  const int swz = (bid & 7) * 32 + (bid >> 3);
  const int bm = (swz & 31) * 128, bn = (swz >> 5) * 256;
  const char* Ag = (const char*)A + (size_t)bm * (KDIM * 2);
  const char* Bg = (const char*)Bw + (size_t)bn * (KDIM * 2);

  f32x4 acc[4][4] = {};

#define STAGE_A(cc, dstb) do {                                                 \
    const int o = tid * 16;                                                    \
    const int r = o >> 6, c = o & 63;                                          \
    gload_lds16(Ag + (size_t)r * (KDIM * 2) + (cc) * 64 +                      \
                (c ^ (((r >> 1) & 3) << 4)),                                   \
                (dstb) + (w << 10));                                           \
  } while (0)

#define STAGE_B(cc, dstb) do { _Pragma("unroll")                               \
    for (int p = 0; p < 2; ++p) {                                              \
      const int o = p * 8192 + tid * 16;                                       \
      const int r = o >> 6, c = o & 63;                                        \
      gload_lds16(Bg + (size_t)r * (KDIM * 2) + (cc) * 64 +                    \
                  (c ^ (((r >> 1) & 3) << 4)),                                 \
                  (dstb) + p * 8192 + (w << 10));                              \
    } } while (0)

  STAGE_A(0, lsA);              STAGE_B(0, lsB);
  STAGE_A(1, lsA + ABYT);       STAGE_B(1, lsB + BBYT);
  STAGE_A(2, lsA + 2 * ABYT);   STAGE_B(2, lsB + 2 * BBYT);
  VM(6);            // chunk 0 landed; 1,2 in flight
  BAR;

  #pragma unroll 1
  for (int t = 0; t < 64; ++t) {
    const int sl = t & 3, s3 = (t + 3) & 3;
    const char* Ac = lsA + sl * ABYT;
    const char* Bc = lsB + sl * BBYT;

    if (t < 61) { STAGE_A(t + 3, lsA + s3 * ABYT); STAGE_B(t + 3, lsB + s3 * BBYT); }

    bf16x8 af[4], bf[4];
    #pragma unroll
    for (int i = 0; i < 4; ++i) {
      const int m = wr * 64 + i * 16 + row16;
      af[i] = *(const bf16x8*)(Ac + m * 64 + ((kg * 16) ^ (((m >> 1) & 3) << 4)));
    }
    #pragma unroll
    for (int j = 0; j < 4; ++j) {
      const int n = wc * 64 + j * 16 + row16;
      bf[j] = *(const bf16x8*)(Bc + n * 64 + ((kg * 16) ^ (((n >> 1) & 3) << 4)));
    }
    PRIO1;
    #pragma unroll
    for (int i = 0; i < 4; ++i)
      #pragma unroll
      for (int j = 0; j < 4; ++j)
        acc[i][j] = mfma16(af[i], bf[j], acc[i][j]);
    PRIO0;
    if (t < 61)       VM(6);   // chunk t+1 landed; t+2,t+3 in flight
    else if (t == 61) VM(3);   // chunk 62 landed
    else if (t == 62) VM(0);   // chunk 63 landed
    BAR;
  }
#undef STAGE_A
#undef STAGE_B

  #pragma unroll
  for (int i = 0; i < 4; ++i) {
    const int row = bm + wr * 64 + i * 16 + kg * 4;
    #pragma unroll
    for (int j = 0; j < 4; ++j) {
      const int col = bn + wc * 64 + j * 16 + row16;
      const float bvj = bias[col];
      #pragma unroll
      for (int r = 0; r < 4; ++r)
        c_out[(size_t)(row + r) * HID + col] = acc[i][j][r] + bvj;
    }
  }
}

// Causal flash attention: swapped QK^T, 32 q-rows/wave, 2-phase dbuf pipeline.
__global__ __launch_bounds__(256, 2) void attn_fwd(
    const unsigned short* __restrict__ Q, const unsigned short* __restrict__ Kk,
    const unsigned short* __restrict__ Vt, unsigned short* __restrict__ O)
{
  __shared__ char lsK[2][64 * 256];
  __shared__ char lsV[2][128 * 128];
  __shared__ char lsP[4][32 * 128];
  const int tid = threadIdx.x, l = tid & 63, w = tid >> 6;
  const int row16 = l & 15, kg = l >> 4;
  const int qb = (blockIdx.y < 16) ? (15 - (int)blockIdx.x) : (int)blockIdx.x;
  const int bh = blockIdx.y;
  const int bidx = bh >> 4, head = bh & 15;

  const char* Qh = (const char*)(Q  + (size_t)bh * S_LEN * DHEAD);
  const char* Kh = (const char*)(Kk + (size_t)bh * S_LEN * DHEAD);
  const char* Vh = (const char*)(Vt + (size_t)bh * DHEAD * S_LEN);

  const int q0w = qb * 128 + w * 32;

  bf16x8 qf[2][4];
  #pragma unroll
  for (int qs = 0; qs < 2; ++qs)
    #pragma unroll
    for (int t = 0; t < 4; ++t)
      qf[qs][t] = *(const bf16x8*)(Qh + ((size_t)(q0w + qs * 16 + row16) * DHEAD + t * 32 + kg * 8) * 2);

  float m[2]  = {-1e30f, -1e30f};
  float ls[2] = {0.f, 0.f};
  f32x4 oacc[2][8] = {};

  const int last = 2 * qb + 1;

#define STAGE(buf, kt_) do {                                                     \
    _Pragma("unroll")                                                            \
    for (int c = 0; c < 4; ++c) {                                                \
      const int o = c * 4096 + tid * 16;                                         \
      const int rk = o >> 8, cbk = (o & 255) ^ ((rk & 7) << 4);                  \
      gload_lds16(Kh + (size_t)((kt_) * 64 + rk) * 256 + cbk,                    \
                  lsK[buf] + c * 4096 + (w << 10));                              \
      const int dv = o >> 7, cbv = (o & 127) ^ ((dv & 7) << 4);                  \
      gload_lds16(Vh + (size_t)dv * 4096 + (size_t)(kt_) * 128 + cbv,            \
                  lsV[buf] + c * 4096 + (w << 10));                              \
    } } while (0)

  STAGE(0, 0);
  __syncthreads();

  int cur = 0;
  for (int kt = 0; ; ++kt) {
    if (kt < last) STAGE(cur ^ 1, kt + 1);

    if (kt * 64 <= q0w + 31) {
      const char* Kc = lsK[cur];
      const char* Vc = lsV[cur];
      char* Pl = lsP[w];

      f32x4 sc[4][2] = {};
      #pragma unroll
      for (int j = 0; j < 4; ++j) {
        const int krow = j * 16 + row16;
        const int sw = (krow & 7) << 4;
        bf16x8 kf[4];
        #pragma unroll
        for (int t = 0; t < 4; ++t)
          kf[t] = *(const bf16x8*)(Kc + krow * 256 + ((t * 64 + kg * 16) ^ sw));
        #pragma unroll
        for (int t = 0; t < 4; ++t) {
          sc[j][0] = mfma16(kf[t], qf[0][t], sc[j][0]);
          sc[j][1] = mfma16(kf[t], qf[1][t], sc[j][1]);
        }
      }

      if (kt >= 2 * qb) {
        #pragma unroll
        for (int j = 0; j < 4; ++j) {
          const int kvb = kt * 64 + j * 16 + kg * 4;
          #pragma unroll
          for (int qs = 0; qs < 2; ++qs) {
            const int qq = q0w + qs * 16 + row16;
            #pragma unroll
            for (int r = 0; r < 4; ++r)
              if (kvb + r > qq) sc[j][qs][r] = -1e30f;
          }
        }
      }

      float pm[2], al[2] = {1.f, 1.f};
      #pragma unroll
      for (int qs = 0; qs < 2; ++qs) {
        float mx = fmaxf(fmaxf(hmax4(sc[0][qs]), hmax4(sc[1][qs])),
                         fmaxf(hmax4(sc[2][qs]), hmax4(sc[3][qs])));
        mx = fmaxf(mx, __shfl_xor(mx, 16, 64));
        mx = fmaxf(mx, __shfl_xor(mx, 32, 64));
        pm[qs] = mx;
      }
      const bool need = (pm[0] > m[0] + 8.f) || (pm[1] > m[1] + 8.f);
      if (__any(need)) {
        const float n0 = fmaxf(m[0], pm[0]), n1 = fmaxf(m[1], pm[1]);
        al[0] = exp2f(m[0] - n0); al[1] = exp2f(m[1] - n1);
        m[0] = n0; m[1] = n1;
        float aq[2][4];
        #pragma unroll
        for (int qs2 = 0; qs2 < 2; ++qs2)
          #pragma unroll
          for (int r = 0; r < 4; ++r)
            aq[qs2][r] = __shfl(al[qs2], kg * 4 + r, 64);
        #pragma unroll
        for (int qs2 = 0; qs2 < 2; ++qs2)
          #pragma unroll
          for (int dt = 0; dt < 8; ++dt)
            #pragma unroll
            for (int r = 0; r < 4; ++r)
              oacc[qs2][dt][r] *= aq[qs2][r];
      }

      #pragma unroll
      for (int qs = 0; qs < 2; ++qs) {
        const int q = qs * 16 + row16;
        const int psw = (q & 7) << 4;
        float ps = 0.f;
        #pragma unroll
        for (int j = 0; j < 4; ++j) {
          const float p0 = exp2f(sc[j][qs][0] - m[qs]);
          const float p1 = exp2f(sc[j][qs][1] - m[qs]);
          const float p2 = exp2f(sc[j][qs][2] - m[qs]);
          const float p3 = exp2f(sc[j][qs][3] - m[qs]);
          ps += (p0 + p1) + (p2 + p3);
          uint2 pw; pw.x = pkbf(p0, p1); pw.y = pkbf(p2, p3);
          *(uint2*)(Pl + q * 128 + ((j * 32 + kg * 8) ^ psw)) = pw;
        }
        ps += __shfl_xor(ps, 16, 64);
        ps += __shfl_xor(ps, 32, 64);
        ls[qs] = ls[qs] * al[qs] + ps;
      }

      bf16x8 pa[2][2];
      #pragma unroll
      for (int qs2 = 0; qs2 < 2; ++qs2) {
        const int q = qs2 * 16 + row16;
        #pragma unroll
        for (int ks = 0; ks < 2; ++ks)
          pa[qs2][ks] = *(const bf16x8*)(Pl + q * 128 + ((ks * 64 + kg * 16) ^ ((q & 7) << 4)));
      }
      #pragma unroll
      for (int dt = 0; dt < 8; ++dt) {
        const int drow = dt * 16 + row16;
        const int vsw = (drow & 7) << 4;
        bf16x8 v0 = *(const bf16x8*)(Vc + drow * 128 + ((kg * 16) ^ vsw));
        bf16x8 v1 = *(const bf16x8*)(Vc + drow * 128 + ((64 + kg * 16) ^ vsw));
        oacc[0][dt] = mfma16(pa[0][0], v0, oacc[0][dt]);
        oacc[0][dt] = mfma16(pa[0][1], v1, oacc[0][dt]);
        oacc[1][dt] = mfma16(pa[1][0], v0, oacc[1][dt]);
        oacc[1][dt] = mfma16(pa[1][1], v1, oacc[1][dt]);
      }
    }

    __syncthreads();
    if (kt == last) break;
    cur ^= 1;
  }
#undef STAGE

  #pragma unroll
  for (int qs2 = 0; qs2 < 2; ++qs2) {
    #pragma unroll
    for (int r = 0; r < 4; ++r) {
      const float lr = __shfl(ls[qs2], kg * 4 + r, 64);
      const float inv = 1.0f / lr;
      const int q = q0w + qs2 * 16 + kg * 4 + r;
      const size_t orow = (size_t)(bidx * S_LEN + q) * HID + (size_t)head * DHEAD;
      #pragma unroll
      for (int dt = 0; dt < 8; ++dt)
        O[orow + dt * 16 + row16] = f2bf(oacc[qs2][dt][r] * inv);
    }
  }
}

extern "C" void kernel_launch(void* const* d_in, const int* in_sizes, int n_in,
                              void* d_out, int out_size, void* d_ws, size_t ws_size,
                              hipStream_t stream) {
  const float* x    = (const float*)d_in[0];
  const float* Wqkv = (const float*)d_in[1];
  const float* bqkv = (const float*)d_in[2];
  const float* Wout = (const float*)d_in[3];
  const float* bout = (const float*)d_in[4];
  float* out = (float*)d_out;

  if (ws_size < 100663296) return;  // insufficient scratch -> clean validation fail
  char* ws = (char*)d_ws;
  unsigned short* Qb    = (unsigned short*)(ws);
  unsigned short* Kb    = (unsigned short*)(ws + 16777216);
  unsigned short* Vtb   = (unsigned short*)(ws + 2 * 16777216);
  unsigned short* xb    = (unsigned short*)(ws + 3 * 16777216);
  unsigned short* Ob    = xb;  // alias: xb dead after QKV GEMM, Ob written after
  unsigned short* Wqkvb = (unsigned short*)(ws + 4 * 16777216);
  unsigned short* Woutb = (unsigned short*)(ws + 4 * 16777216 + 25165824);

  cvt_bf16<<<2048, 256, 0, stream>>>(x,    xb,    4096 * 2048);
  cvt_bf16<<<2048, 256, 0, stream>>>(Wqkv, Wqkvb, 6144 * 2048);
  cvt_bf16<<<1024, 256, 0, stream>>>(Wout, Woutb, 2048 * 2048);

  gemm_qkv<<<256, 512, 0, stream>>>(xb, Wqkvb, bqkv, Qb, Kb, Vtb);
  attn_fwd<<<dim3(16, 32), 256, 0, stream>>>(Qb, Kb, Vtb, Ob);
  gemm_out<<<256, 512, 0, stream>>>(Ob, Woutb, bout, out);
}